// Round 8
// baseline (184.485 us; speedup 1.0000x reference)
//
#include <hip/hip_runtime.h>

#define D_ 64
#define H_ 128
#define W_ 128
#define VOL (D_*H_*W_)   // 1048576 = 1<<20
#define NF 4             // {pred,target} x {b0,b1}
#define LARGEF 1e8f
#define SW(r,c) (((r) << 7) + ((c) ^ ((r) & 31)))   // bank-conflict-free both axes

__device__ __forceinline__ bool maskv(float v, int which) {
  // which==0: pred mask = sigmoid(v)>0.5 <=> v>0 ; which==1: target != 0
  return which ? (v != 0.0f) : (v > 0.0f);
}

// ---- fused init (erosion/surface) + z two-scan EDT. One thread per column.
__global__ __launch_bounds__(256) void k_initz(const float* __restrict__ pred,
                                               const float* __restrict__ targ,
                                               float* __restrict__ d2,
                                               double* __restrict__ acc) {
  __shared__ unsigned short fwd[D_][256];            // u16: 2-way banks = free
  int g = blockIdx.x * 256 + threadIdx.x;            // 65536 columns
  if (g < 2) acc[g] = 0.0;                           // ws is poisoned each call
  int f = g >> 14, yx = g & 16383;
  int which = f & 1;
  const float* __restrict__ src = (which ? targ : pred) + ((size_t)(f >> 1) << 20);
  int y = yx >> 7, x = yx & 127;
  bool mzm = false;                                  // z-1 mask (border=false)
  bool mz  = maskv(src[yx], which);                  // z mask
  int d = 16384;
  for (int z = 0; z < D_; ++z) {
    bool mzp = (z < D_ - 1) ? maskv(src[((z + 1) << 14) + yx], which) : false;
    bool er = mz && mzm && mzp;
    er = er && (y > 0)   && maskv(src[(z << 14) + yx - 128], which);
    er = er && (y < 127) && maskv(src[(z << 14) + yx + 128], which);
    er = er && (x > 0)   && maskv(src[(z << 14) + yx - 1], which);
    er = er && (x < 127) && maskv(src[(z << 14) + yx + 1], which);
    bool surf = mz && !er;                           // surface = m && !eroded
    d = surf ? 0 : min(d + 1, 16384);
    fwd[z][threadIdx.x] = (unsigned short)d;
    mzm = mz; mz = mzp;
  }
  int dd = 16384;                                    // column thread-private: no sync
  for (int z = D_ - 1; z >= 0; --z) {
    int fv = fwd[z][threadIdx.x];
    dd = (fv == 0) ? 0 : min(dd + 1, 16384);
    int r = min(fv, dd);
    d2[(f << 20) + (z << 14) + yx] = (r >= 16384) ? LARGEF : (float)(r * r);
  }
}

// ---- fused y+x EDT on one (f,z) slab held in 64KB swizzled LDS.
// 1024 thr: 128 lines x 8 waves, R=16 outputs/thread, 2 VALU/pair.
// Writes final dist = sqrt(d2) in place.
__global__ __launch_bounds__(1024) void k_edt_yx(float* __restrict__ d2) {
  __shared__ float tile[128 * 128];                  // exactly 64 KB
  int f = blockIdx.y, z = blockIdx.x;
  float* base = d2 + (f << 20) + (z << 14);
  for (int e = threadIdx.x; e < 16384; e += 1024) {  // stage + y-fold (+y^2)
    int r = e >> 7, c = e & 127;                     // r=y, c=x
    tile[SW(r, c)] = base[e] + (float)(r * r);
  }
  __syncthreads();
  const int R = 16;
  int tp = threadIdx.x & 127, tw = threadIdx.x >> 7; // tw in [0,8)
  float best[R], fi[R];
  float fb = (float)(tw * R);
  // ---- y-pass: tp = x column; outputs i in [16tw,16tw+16)
  #pragma unroll
  for (int u = 0; u < R; ++u) { best[u] = 3.0e8f; fi[u] = fb + (float)u; }
  #pragma unroll 2
  for (int j = 0; j < H_; ++j) {
    float t = tile[SW(j, tp)];
    float m2j = -2.0f * (float)j;
    #pragma unroll
    for (int u = 0; u < R; ++u)
      best[u] = fminf(best[u], __builtin_fmaf(m2j, fi[u], t));
  }
  __syncthreads();                                   // all rows read before overwrite
  float fx2 = (float)(tp * tp);                      // x-fold (+x^2) for next pass
  #pragma unroll
  for (int u = 0; u < R; ++u)
    tile[SW(tw * R + u, tp)] = best[u] + fi[u] * fi[u] + fx2;
  __syncthreads();
  // ---- x-pass: tp = y line; outputs xi in [16tw,16tw+16)
  #pragma unroll
  for (int u = 0; u < R; ++u) best[u] = 3.0e8f;
  #pragma unroll 2
  for (int j = 0; j < W_; ++j) {
    float t = tile[SW(tp, j)];
    float m2j = -2.0f * (float)j;
    #pragma unroll
    for (int u = 0; u < R; ++u)
      best[u] = fminf(best[u], __builtin_fmaf(m2j, fi[u], t));
  }
  __syncthreads();
  #pragma unroll
  for (int u = 0; u < R; ++u)
    tile[SW(tp, tw * R + u)] = sqrtf(best[u] + fi[u] * fi[u]);
  __syncthreads();
  for (int e = threadIdx.x; e < 16384; e += 1024)    // coalesced writeback
    base[e] = tile[SW(e >> 7, e & 127)];
}

// ---- smooth-L1 over dist arrays (sqrt already applied), double accumulation.
__global__ __launch_bounds__(256) void k_reduce(const float* __restrict__ d2,
                                               double* __restrict__ acc) {
  int b = blockIdx.y;
  const float4* dp = (const float4*)(d2 + ((size_t)(b * 2 + 0) << 20));
  const float4* dt = (const float4*)(d2 + ((size_t)(b * 2 + 1) << 20));
  double s = 0.0;
  for (int v = blockIdx.x * 256 + threadIdx.x; v < VOL / 4; v += gridDim.x * 256) {
    float4 a = dp[v], c = dt[v];
    float d0 = a.x - c.x, d1 = a.y - c.y, d2v = a.z - c.z, d3 = a.w - c.w;
    float a0 = fabsf(d0), a1 = fabsf(d1), a2 = fabsf(d2v), a3 = fabsf(d3);
    s += (double)(a0 < 1.0f ? 0.5f * d0 * d0 : a0 - 0.5f);
    s += (double)(a1 < 1.0f ? 0.5f * d1 * d1 : a1 - 0.5f);
    s += (double)(a2 < 1.0f ? 0.5f * d2v * d2v : a2 - 0.5f);
    s += (double)(a3 < 1.0f ? 0.5f * d3 * d3 : a3 - 0.5f);
  }
  for (int o = 32; o > 0; o >>= 1) s += __shfl_down(s, o);
  __shared__ double wsum[4];
  if ((threadIdx.x & 63) == 0) wsum[threadIdx.x >> 6] = s;
  __syncthreads();
  if (threadIdx.x == 0)
    atomicAdd(&acc[b], wsum[0] + wsum[1] + wsum[2] + wsum[3]);
}

__global__ void k_final(const double* __restrict__ acc, float* __restrict__ out) {
  if (threadIdx.x == 0 && blockIdx.x == 0)
    out[0] = (float)(0.5 * (acc[0] / (double)VOL + acc[1] / (double)VOL));
}

extern "C" void kernel_launch(void* const* d_in, const int* in_sizes, int n_in,
                              void* d_out, int out_size, void* d_ws, size_t ws_size,
                              hipStream_t stream) {
  const float* pred = (const float*)d_in[0];
  const float* targ = (const float*)d_in[1];
  float*  d2  = (float*)d_ws;
  double* acc = (double*)((char*)d_ws + (size_t)NF * VOL * sizeof(float));
  float*  out = (float*)d_out;

  k_initz <<<NF * H_ * W_ / 256, 256, 0, stream>>>(pred, targ, d2, acc);
  k_edt_yx<<<dim3(D_, NF), 1024, 0, stream>>>(d2);
  k_reduce<<<dim3(256, 2), 256, 0, stream>>>(d2, acc);
  k_final <<<1, 64, 0, stream>>>(acc, out);
}

// Round 10
// 145.970 us; speedup vs baseline: 1.2639x; 1.2639x over previous
//
#include <hip/hip_runtime.h>

#define D_ 64
#define H_ 128
#define W_ 128
#define VOL (D_*H_*W_)   // 1048576 = 1<<20
#define NF 4             // {pred,target} x {b0,b1}
#define LARGEF 1e8f
#define SW(r,c) (((r) << 7) + ((c) ^ ((r) & 31)))   // bank-conflict-free both axes

__device__ __forceinline__ bool maskv(float v, int which) {
  // which==0: pred mask = sigmoid(v)>0.5 <=> v>0 ; which==1: target != 0
  return which ? (v != 0.0f) : (v > 0.0f);
}

// ---- elementwise surface extraction -> 1 byte/voxel. Massively parallel so
// the 7 neighbor loads are latency-hidden by TLP (this was the round-8 regression:
// doing these loads inside the 256-block column scan had no TLP to hide them).
__global__ __launch_bounds__(256) void k_init(const float* __restrict__ pred,
                                              const float* __restrict__ targ,
                                              unsigned char* __restrict__ surf,
                                              double* __restrict__ acc) {
  int idx = blockIdx.x * 256 + threadIdx.x;          // [0, NF*VOL)
  if (idx < 2) acc[idx] = 0.0;                       // ws is poisoned each call
  int f = idx >> 20;
  int v = idx & (VOL - 1);
  int which = f & 1;
  const float* __restrict__ src = (which ? targ : pred) + ((size_t)(f >> 1) << 20);
  int z = v >> 14, y = (v >> 7) & 127, x = v & 127;
  bool m = maskv(src[v], which);
  bool s = false;
  if (m) {
    bool er = true;
    er = er && (z > 0)      && maskv(src[v - H_*W_], which);
    er = er && (z < D_ - 1) && maskv(src[v + H_*W_], which);
    er = er && (y > 0)      && maskv(src[v - W_], which);
    er = er && (y < H_ - 1) && maskv(src[v + W_], which);
    er = er && (x > 0)      && maskv(src[v - 1], which);
    er = er && (x < W_ - 1) && maskv(src[v + 1], which);
    s = !er;                                         // surface = m && !eroded
  }
  surf[idx] = (unsigned char)s;
}

// ---- z two-scan EDT over surface bytes -> u8 z-dist (255 = no surface).
// One thread per (f,y,x) column; light 64B/wave plane accesses, in LDS u16.
__global__ __launch_bounds__(256) void k_zscan(const unsigned char* __restrict__ surf,
                                               unsigned char* __restrict__ zdist) {
  __shared__ unsigned short fwd[D_][256];            // u16: 2-way banks = free
  int g = blockIdx.x * 256 + threadIdx.x;            // 65536 columns
  int f = g >> 14, yx = g & 16383;
  const unsigned char* s = surf + (f << 20) + yx;
  unsigned char* o = zdist + (f << 20) + yx;
  int d = 255;
  #pragma unroll 4
  for (int z = 0; z < D_; ++z) {
    d = s[z << 14] ? 0 : min(d + 1, 255);            // fv in {255} U [0,63]
    fwd[z][threadIdx.x] = (unsigned short)d;
  }
  int dd = 255;                                      // column thread-private: no sync
  #pragma unroll 4
  for (int z = D_ - 1; z >= 0; --z) {
    int fv = fwd[z][threadIdx.x];
    dd = (fv == 0) ? 0 : min(dd + 1, 255);
    o[z << 14] = (unsigned char)min(fv, dd);         // in {255} U [0,63]
  }
}

// ---- fused y+x EDT on one (f,z) slab held in 64KB swizzled LDS.
// 1024 thr: 128 lines x 8 waves, R=16 outputs/thread, 2 VALU/pair.
// Decodes u8 z-dist at stage; writes final dist = sqrt(d2).
__global__ __launch_bounds__(1024) void k_edt_yx(const unsigned char* __restrict__ zdist,
                                                 float* __restrict__ dist) {
  __shared__ float tile[128 * 128];                  // exactly 64 KB
  int f = blockIdx.y, z = blockIdx.x;
  const unsigned char* zsrc = zdist + (f << 20) + (z << 14);
  float* dbase = dist + (f << 20) + (z << 14);
  for (int e = threadIdx.x; e < 16384; e += 1024) {  // stage: decode + y-fold (+y^2)
    int r = e >> 7, c = e & 127;                     // r=y, c=x
    int b = zsrc[e];
    float v = (b == 255) ? LARGEF : (float)(b * b);
    tile[SW(r, c)] = v + (float)(r * r);
  }
  __syncthreads();
  const int R = 16;
  int tp = threadIdx.x & 127, tw = threadIdx.x >> 7; // tw in [0,8)
  float best[R], fi[R];
  float fb = (float)(tw * R);
  // ---- y-pass: tp = x column; outputs i in [16tw,16tw+16)
  #pragma unroll
  for (int u = 0; u < R; ++u) { best[u] = 3.0e8f; fi[u] = fb + (float)u; }
  #pragma unroll 2
  for (int j = 0; j < H_; ++j) {
    float t = tile[SW(j, tp)];
    float m2j = -2.0f * (float)j;
    #pragma unroll
    for (int u = 0; u < R; ++u)
      best[u] = fminf(best[u], __builtin_fmaf(m2j, fi[u], t));
  }
  __syncthreads();                                   // all rows read before overwrite
  float fx2 = (float)(tp * tp);                      // x-fold (+x^2) for next pass
  #pragma unroll
  for (int u = 0; u < R; ++u)
    tile[SW(tw * R + u, tp)] = best[u] + fi[u] * fi[u] + fx2;
  __syncthreads();
  // ---- x-pass: tp = y line; outputs xi in [16tw,16tw+16)
  #pragma unroll
  for (int u = 0; u < R; ++u) best[u] = 3.0e8f;
  #pragma unroll 2
  for (int j = 0; j < W_; ++j) {
    float t = tile[SW(tp, j)];
    float m2j = -2.0f * (float)j;
    #pragma unroll
    for (int u = 0; u < R; ++u)
      best[u] = fminf(best[u], __builtin_fmaf(m2j, fi[u], t));
  }
  __syncthreads();
  #pragma unroll
  for (int u = 0; u < R; ++u)
    tile[SW(tp, tw * R + u)] = sqrtf(best[u] + fi[u] * fi[u]);
  __syncthreads();
  for (int e = threadIdx.x; e < 16384; e += 1024)    // coalesced writeback
    dbase[e] = tile[SW(e >> 7, e & 127)];
}

// ---- smooth-L1 over dist arrays (sqrt already applied), double accumulation.
__global__ __launch_bounds__(256) void k_reduce(const float* __restrict__ dist,
                                               double* __restrict__ acc) {
  int b = blockIdx.y;
  const float4* dp = (const float4*)(dist + ((size_t)(b * 2 + 0) << 20));
  const float4* dt = (const float4*)(dist + ((size_t)(b * 2 + 1) << 20));
  double s = 0.0;
  for (int v = blockIdx.x * 256 + threadIdx.x; v < VOL / 4; v += gridDim.x * 256) {
    float4 a = dp[v], c = dt[v];
    float d0 = a.x - c.x, d1 = a.y - c.y, d2v = a.z - c.z, d3 = a.w - c.w;
    float a0 = fabsf(d0), a1 = fabsf(d1), a2 = fabsf(d2v), a3 = fabsf(d3);
    s += (double)(a0 < 1.0f ? 0.5f * d0 * d0 : a0 - 0.5f);
    s += (double)(a1 < 1.0f ? 0.5f * d1 * d1 : a1 - 0.5f);
    s += (double)(a2 < 1.0f ? 0.5f * d2v * d2v : a2 - 0.5f);
    s += (double)(a3 < 1.0f ? 0.5f * d3 * d3 : a3 - 0.5f);
  }
  for (int o = 32; o > 0; o >>= 1) s += __shfl_down(s, o);
  __shared__ double wsum[4];
  if ((threadIdx.x & 63) == 0) wsum[threadIdx.x >> 6] = s;
  __syncthreads();
  if (threadIdx.x == 0)
    atomicAdd(&acc[b], wsum[0] + wsum[1] + wsum[2] + wsum[3]);
}

__global__ void k_final(const double* __restrict__ acc, float* __restrict__ out) {
  if (threadIdx.x == 0 && blockIdx.x == 0)
    out[0] = (float)(0.5 * (acc[0] / (double)VOL + acc[1] / (double)VOL));
}

extern "C" void kernel_launch(void* const* d_in, const int* in_sizes, int n_in,
                              void* d_out, int out_size, void* d_ws, size_t ws_size,
                              hipStream_t stream) {
  const float* pred = (const float*)d_in[0];
  const float* targ = (const float*)d_in[1];
  unsigned char* surf  = (unsigned char*)d_ws;                       // 4 MB
  unsigned char* zdist = (unsigned char*)d_ws + ((size_t)NF << 20);  // 4 MB
  float*  dist = (float*)((char*)d_ws + ((size_t)NF << 21));         // 16 MB
  double* acc  = (double*)((char*)d_ws + ((size_t)NF << 21) + ((size_t)NF * VOL * 4));
  float*  out  = (float*)d_out;

  k_init  <<<NF * VOL / 256, 256, 0, stream>>>(pred, targ, surf, acc);
  k_zscan <<<NF * H_ * W_ / 256, 256, 0, stream>>>(surf, zdist);
  k_edt_yx<<<dim3(D_, NF), 1024, 0, stream>>>(zdist, dist);
  k_reduce<<<dim3(256, 2), 256, 0, stream>>>(dist, acc);
  k_final <<<1, 64, 0, stream>>>(acc, out);
}

// Round 13
// 112.816 us; speedup vs baseline: 1.6353x; 1.2939x over previous
//
#include <hip/hip_runtime.h>

#define D_ 64
#define H_ 128
#define W_ 128
#define VOL (D_*H_*W_)   // 1048576 = 1<<20
#define NF 4             // {pred,target} x {b0,b1}
#define LARGEF 1e8f
#define SW(r,c) (((r) << 7) + ((c) ^ ((r) & 31)))   // bank-conflict-free both axes

__device__ __forceinline__ bool maskv(float v, int which) {
  // which==0: pred mask = sigmoid(v)>0.5 <=> v>0 ; which==1: target != 0
  return which ? (v != 0.0f) : (v > 0.0f);
}

// ---- surface extraction, 4 voxels/thread: 5 float4 + 2 scalar loads instead
// of 28 scalar; uchar4 coalesced store. Massive TLP hides latency.
__global__ __launch_bounds__(256) void k_init(const float* __restrict__ pred,
                                              const float* __restrict__ targ,
                                              unsigned char* __restrict__ surf,
                                              double* __restrict__ acc) {
  int idx = blockIdx.x * 256 + threadIdx.x;          // [0, NF*VOL/4)
  if (idx < 2) acc[idx] = 0.0;                       // ws is poisoned each call
  int f = idx >> 18;                                 // VOL/4 = 2^18
  int q = idx & 262143;
  int which = f & 1;
  const float* __restrict__ src = (which ? targ : pred) + ((size_t)(f >> 1) << 20);
  const float4* __restrict__ s4 = (const float4*)src;
  int v = q << 2;
  int z = v >> 14, y = (v >> 7) & 127, x = v & 127;  // x multiple of 4
  float4 c = s4[q];
  bool m0 = maskv(c.x, which), m1 = maskv(c.y, which);
  bool m2 = maskv(c.z, which), m3 = maskv(c.w, which);
  bool ym0=false, ym1=false, ym2=false, ym3=false;
  bool yp0=false, yp1=false, yp2=false, yp3=false;
  bool zm0=false, zm1=false, zm2=false, zm3=false;
  bool zp0=false, zp1=false, zp2=false, zp3=false;
  if (y > 0)   { float4 t = s4[q - 32];   ym0=maskv(t.x,which); ym1=maskv(t.y,which); ym2=maskv(t.z,which); ym3=maskv(t.w,which); }
  if (y < 127) { float4 t = s4[q + 32];   yp0=maskv(t.x,which); yp1=maskv(t.y,which); yp2=maskv(t.z,which); yp3=maskv(t.w,which); }
  if (z > 0)   { float4 t = s4[q - 4096]; zm0=maskv(t.x,which); zm1=maskv(t.y,which); zm2=maskv(t.z,which); zm3=maskv(t.w,which); }
  if (z < 63)  { float4 t = s4[q + 4096]; zp0=maskv(t.x,which); zp1=maskv(t.y,which); zp2=maskv(t.z,which); zp3=maskv(t.w,which); }
  bool lm = (x > 0)   ? maskv(src[v - 1], which) : false;
  bool rm = (x < 124) ? maskv(src[v + 4], which) : false;
  bool e0 = m0 && lm && m1 && ym0 && yp0 && zm0 && zp0;
  bool e1 = m1 && m0 && m2 && ym1 && yp1 && zm1 && zp1;
  bool e2 = m2 && m1 && m3 && ym2 && yp2 && zm2 && zp2;
  bool e3 = m3 && m2 && rm && ym3 && yp3 && zm3 && zp3;
  uchar4 o;
  o.x = (unsigned char)(m0 && !e0);
  o.y = (unsigned char)(m1 && !e1);
  o.z = (unsigned char)(m2 && !e2);
  o.w = (unsigned char)(m3 && !e3);
  ((uchar4*)surf)[idx] = o;                          // surface = m && !eroded
}

// ---- z two-scan EDT over surface bytes -> u8 z-dist (255 = no surface).
// One thread per (f,y,x) column; unroll 16 keeps many loads in flight.
__global__ __launch_bounds__(256) void k_zscan(const unsigned char* __restrict__ surf,
                                               unsigned char* __restrict__ zdist) {
  __shared__ unsigned short fwd[D_][256];            // u16: 2-way banks = free
  int g = blockIdx.x * 256 + threadIdx.x;            // 65536 columns
  int f = g >> 14, yx = g & 16383;
  const unsigned char* s = surf + (f << 20) + yx;
  unsigned char* o = zdist + (f << 20) + yx;
  int d = 255;
  #pragma unroll 16
  for (int z = 0; z < D_; ++z) {
    d = s[z << 14] ? 0 : min(d + 1, 255);            // fv in {255} U [0,63]
    fwd[z][threadIdx.x] = (unsigned short)d;
  }
  int dd = 255;                                      // column thread-private: no sync
  #pragma unroll 8
  for (int z = D_ - 1; z >= 0; --z) {
    int fv = fwd[z][threadIdx.x];
    dd = (fv == 0) ? 0 : min(dd + 1, 255);
    o[z << 14] = (unsigned char)min(fv, dd);         // in {255} U [0,63]
  }
}

// ---- fused y+x EDT on one (f,z) slab in 64KB swizzled LDS, with EXACT
// window pruning: best[i] <= t[i] (the j=i candidate), so only j with
// (i-j)^2 < t[i] can win -> wave-uniform window of ~2*sqrt(tmax)+16.
// floor(sqrtf(exact int)) never under-estimates; excluded ties can't change
// the min value. Candidates kept are computed bit-identically to the full loop.
__global__ __launch_bounds__(1024) void k_edt_yx(const unsigned char* __restrict__ zdist,
                                                 float* __restrict__ dist) {
  __shared__ float tile[128 * 128];                  // exactly 64 KB
  int f = blockIdx.y, z = blockIdx.x;
  const unsigned char* zsrc = zdist + (f << 20) + (z << 14);
  float* dbase = dist + (f << 20) + (z << 14);
  for (int e = threadIdx.x; e < 16384; e += 1024) {  // stage: decode + y-fold (+y^2)
    int r = e >> 7, c = e & 127;                     // r=y, c=x
    int b = zsrc[e];
    float v = (b == 255) ? LARGEF : (float)(b * b);
    tile[SW(r, c)] = v + (float)(r * r);             // tile[y][x] = zd^2 + y^2
  }
  __syncthreads();
  const int R = 16;
  int tp = threadIdx.x & 127, tw = threadIdx.x >> 7; // tw in [0,8), wave-uniform
  float best[R], fi[R];
  float fb = (float)(tw * R);
  // ---- y-pass: tp = x column; outputs i in [16tw,16tw+16)
  float tmax = 0.0f;
  #pragma unroll
  for (int u = 0; u < R; ++u) {
    fi[u] = fb + (float)u; best[u] = 3.0e8f;
    float tv = tile[SW(tw * R + u, tp)] - fi[u] * fi[u];  // = zd^2(i,tp), exact
    tmax = fmaxf(tmax, tv);
  }
  #pragma unroll
  for (int o = 1; o < 64; o <<= 1) tmax = fmaxf(tmax, __shfl_xor(tmax, o));
  int rad = (int)sqrtf(tmax);
  int jlo = max(0, tw * R - rad), jhi = min(H_ - 1, tw * R + (R - 1) + rad);
  for (int j = jlo; j <= jhi; ++j) {
    float t = tile[SW(j, tp)];                       // zd^2 + j^2
    float m2j = -2.0f * (float)j;
    #pragma unroll
    for (int u = 0; u < R; ++u)
      best[u] = fminf(best[u], __builtin_fmaf(m2j, fi[u], t));
  }
  __syncthreads();                                   // all rows read before overwrite
  float fx2 = (float)(tp * tp);                      // +x^2 fold for the x-pass
  #pragma unroll
  for (int u = 0; u < R; ++u)
    tile[SW(tw * R + u, tp)] = best[u] + fi[u] * fi[u] + fx2;  // yEDT(i,tp)+tp^2
  __syncthreads();
  // ---- x-pass: tp = y line; outputs xi in [16tw,16tw+16).
  // tile[SW(tp, j)] = yEDT(tp, j) + j^2  -> the +j^2 fold is exactly what the
  // candidate needs; do NOT subtract anything (round-10 bug: subtracted y^2).
  tmax = 0.0f;
  #pragma unroll
  for (int u = 0; u < R; ++u) {
    best[u] = 3.0e8f;
    float tv = tile[SW(tp, tw * R + u)] - fi[u] * fi[u];  // = yEDT(tp,i), exact
    tmax = fmaxf(tmax, tv);
  }
  #pragma unroll
  for (int o = 1; o < 64; o <<= 1) tmax = fmaxf(tmax, __shfl_xor(tmax, o));
  rad = (int)sqrtf(tmax);
  jlo = max(0, tw * R - rad); jhi = min(W_ - 1, tw * R + (R - 1) + rad);
  for (int j = jlo; j <= jhi; ++j) {
    float t = tile[SW(tp, j)];                       // yEDT + j^2
    float m2j = -2.0f * (float)j;
    #pragma unroll
    for (int u = 0; u < R; ++u)
      best[u] = fminf(best[u], __builtin_fmaf(m2j, fi[u], t));
  }
  __syncthreads();
  #pragma unroll
  for (int u = 0; u < R; ++u)
    tile[SW(tp, tw * R + u)] = sqrtf(best[u] + fi[u] * fi[u]);
  __syncthreads();
  for (int e = threadIdx.x; e < 16384; e += 1024)    // coalesced writeback
    dbase[e] = tile[SW(e >> 7, e & 127)];
}

// ---- smooth-L1 over dist arrays (sqrt already applied), double accumulation.
__global__ __launch_bounds__(256) void k_reduce(const float* __restrict__ dist,
                                               double* __restrict__ acc) {
  int b = blockIdx.y;
  const float4* dp = (const float4*)(dist + ((size_t)(b * 2 + 0) << 20));
  const float4* dt = (const float4*)(dist + ((size_t)(b * 2 + 1) << 20));
  double s = 0.0;
  for (int v = blockIdx.x * 256 + threadIdx.x; v < VOL / 4; v += gridDim.x * 256) {
    float4 a = dp[v], c = dt[v];
    float d0 = a.x - c.x, d1 = a.y - c.y, d2v = a.z - c.z, d3 = a.w - c.w;
    float a0 = fabsf(d0), a1 = fabsf(d1), a2 = fabsf(d2v), a3 = fabsf(d3);
    s += (double)(a0 < 1.0f ? 0.5f * d0 * d0 : a0 - 0.5f);
    s += (double)(a1 < 1.0f ? 0.5f * d1 * d1 : a1 - 0.5f);
    s += (double)(a2 < 1.0f ? 0.5f * d2v * d2v : a2 - 0.5f);
    s += (double)(a3 < 1.0f ? 0.5f * d3 * d3 : a3 - 0.5f);
  }
  for (int o = 32; o > 0; o >>= 1) s += __shfl_down(s, o);
  __shared__ double wsum[4];
  if ((threadIdx.x & 63) == 0) wsum[threadIdx.x >> 6] = s;
  __syncthreads();
  if (threadIdx.x == 0)
    atomicAdd(&acc[b], wsum[0] + wsum[1] + wsum[2] + wsum[3]);
}

__global__ void k_final(const double* __restrict__ acc, float* __restrict__ out) {
  if (threadIdx.x == 0 && blockIdx.x == 0)
    out[0] = (float)(0.5 * (acc[0] / (double)VOL + acc[1] / (double)VOL));
}

extern "C" void kernel_launch(void* const* d_in, const int* in_sizes, int n_in,
                              void* d_out, int out_size, void* d_ws, size_t ws_size,
                              hipStream_t stream) {
  const float* pred = (const float*)d_in[0];
  const float* targ = (const float*)d_in[1];
  unsigned char* surf  = (unsigned char*)d_ws;                       // 4 MB
  unsigned char* zdist = (unsigned char*)d_ws + ((size_t)NF << 20);  // 4 MB
  float*  dist = (float*)((char*)d_ws + ((size_t)NF << 21));         // 16 MB
  double* acc  = (double*)((char*)d_ws + ((size_t)NF << 21) + ((size_t)NF * VOL * 4));
  float*  out  = (float*)d_out;

  k_init  <<<NF * VOL / 4 / 256, 256, 0, stream>>>(pred, targ, surf, acc);
  k_zscan <<<NF * H_ * W_ / 256, 256, 0, stream>>>(surf, zdist);
  k_edt_yx<<<dim3(D_, NF), 1024, 0, stream>>>(zdist, dist);
  k_reduce<<<dim3(256, 2), 256, 0, stream>>>(dist, acc);
  k_final <<<1, 64, 0, stream>>>(acc, out);
}